// Round 9
// baseline (283.293 us; speedup 1.0000x reference)
//
#include <hip/hip_runtime.h>

// GraphSAGE 2-layer. N=40000, E=640000, 128 -> 512 (relu) -> 256.
// Round 16: LDS alias. Round-15 fusion worked (gemm_fused 55.4 us, traffic
// 164->76 MB) but occupancy 33% = ~1.3 effective blocks/CU: LDS 48 KB
// (Apan 16 + Hpan 32) caps residency at 3 and the serial per-block chain
// (stage->K1->epi1->K2->epi2) has nothing to overlap with. Apan is dead
// after K-loop-1's last read and Hpan is written only after that point ->
// ONE 32 KB buffer serves both (extra barrier between K1 and epilogue-1
// makes the overwrite safe; 3 barriers total). LDS 32 KB -> 4 blocks/CU
// = 32 waves/CU (slot cap). Everything else unchanged from round-15.

#define N_NODES 40000
#define N_EDGES 640000
#define F_IN 128
#define F_HID 512
#define F_OUT 256
#define NB_SCAN 157  // ceil(40000/256)

typedef unsigned short ushort_t;
typedef __attribute__((ext_vector_type(8))) short bf16x8;
typedef __attribute__((ext_vector_type(4))) float floatx4;

__device__ __forceinline__ ushort_t f2bf(float f) {
  union { float f; unsigned int u; } x; x.f = f;
  unsigned int r = (x.u + 0x7FFFu + ((x.u >> 16) & 1u)) >> 16;  // RNE
  return (ushort_t)r;
}
__device__ __forceinline__ float bf2f(ushort_t u) {
  union { unsigned int u; float f; } x; x.u = ((unsigned int)u) << 16;
  return x.f;
}

// ---------------- CSR build (scans + fill) ----------------
__global__ void scanA_kernel(const int* __restrict__ deg, int* __restrict__ bsum) {
  __shared__ int sdata[256];
  int i = blockIdx.x * 256 + threadIdx.x;
  sdata[threadIdx.x] = (i < N_NODES) ? deg[i] : 0;
  __syncthreads();
  #pragma unroll
  for (int off = 128; off > 0; off >>= 1) {
    if (threadIdx.x < off) sdata[threadIdx.x] += sdata[threadIdx.x + off];
    __syncthreads();
  }
  if (threadIdx.x == 0) bsum[blockIdx.x] = sdata[0];
}

__global__ void scanB_kernel(const int* __restrict__ bsum, int* __restrict__ boff) {
  __shared__ int buf[2][256];
  int tid = threadIdx.x;
  int v = (tid < NB_SCAN) ? bsum[tid] : 0;
  buf[0][tid] = v;
  __syncthreads();
  int cur = 0;
  #pragma unroll
  for (int off = 1; off < 256; off <<= 1) {
    int val = buf[cur][tid];
    if (tid >= off) val += buf[cur][tid - off];
    buf[cur ^ 1][tid] = val;
    __syncthreads();
    cur ^= 1;
  }
  if (tid < NB_SCAN) boff[tid] = buf[cur][tid] - v;  // exclusive
}

__global__ void scanC_kernel(const int* __restrict__ deg, const int* __restrict__ boff,
                             int* __restrict__ rowptr, int* __restrict__ cursor) {
  __shared__ int buf[2][256];
  int tid = threadIdx.x;
  int i = blockIdx.x * 256 + tid;
  int v = (i < N_NODES) ? deg[i] : 0;
  buf[0][tid] = v;
  __syncthreads();
  int cur = 0;
  #pragma unroll
  for (int off = 1; off < 256; off <<= 1) {
    int val = buf[cur][tid];
    if (tid >= off) val += buf[cur][tid - off];
    buf[cur ^ 1][tid] = val;
    __syncthreads();
    cur ^= 1;
  }
  if (i < N_NODES) {
    int ex = boff[blockIdx.x] + buf[cur][tid] - v;
    rowptr[i] = ex;
    cursor[i] = ex;
    if (i == N_NODES - 1) rowptr[N_NODES] = ex + v;  // == E
  }
}

__global__ void fill_kernel(const int* __restrict__ ei, int* __restrict__ cursor,
                            int* __restrict__ col) {
  int e = blockIdx.x * blockDim.x + threadIdx.x;
  if (e < N_EDGES) {
    int d = ei[N_EDGES + e];
    int s = ei[e];
    int pos = atomicAdd(&cursor[d], 1);
    col[pos] = s;
  }
}

// ---------------- fused preprocessing ----------------
// Wp pack: element (n_global = rowoff+n, k_global = koff+k) at
//   Wp[((gg*(KT/32) + t)*4 + ni)*512 + (qk*16 + lm)*8 + j]
// gg=n>>6, ni=(n>>4)&3, lm=n&15, c=kg>>3, j=kg&7, t=c>>2, qk=c&3.
__device__ __forceinline__ void wp_body(const float* __restrict__ W,
                                        ushort_t* __restrict__ Wp,
                                        int i, int K, int N, int rowoff, int koff,
                                        int KT) {
  if (i < K * N) {
    int n = i / K, k = i - n * K;
    int ng = rowoff + n, kg = koff + k;
    int gg = ng >> 6, ni = (ng >> 4) & 3, lm = ng & 15;
    int c = kg >> 3, j = kg & 7, t = c >> 2, qk = c & 3;
    size_t dst = (((size_t)(gg * (KT / 32) + t) * 4 + ni) * 64 + qk * 16 + lm) * 8 + j;
    Wp[dst] = f2bf(W[(size_t)k * N + n]);
  }
}

// block ranges: [0,5000) cvt_x | [5000,5256) W1l | [5256,5512) W1r
// [5512,6024) W2l | [6024,6536) W2r | [6536,6538) biascat | [6538,9038) deg
#define PREP_BLOCKS 9038
__global__ void prep_kernel(const float* __restrict__ x, ushort_t* __restrict__ xb,
                            const float* __restrict__ W1l, const float* __restrict__ W1r,
                            const float* __restrict__ W2l, const float* __restrict__ W2r,
                            ushort_t* __restrict__ Wp1, ushort_t* __restrict__ Wp2,
                            const float* __restrict__ b2, float* __restrict__ bc,
                            const int* __restrict__ ei, int* __restrict__ deg) {
  int b = blockIdx.x, tid = threadIdx.x;
  if (b < 5000) {
    int i = b * 256 + tid;  // per float4
    const int n4 = (N_NODES * F_IN) / 4;
    if (i < n4) {
      float4 v = ((const float4*)x)[i];
      ushort4 o;
      o.x = f2bf(v.x); o.y = f2bf(v.y); o.z = f2bf(v.z); o.w = f2bf(v.w);
      ((ushort4*)xb)[i] = o;
    }
  } else if (b < 5256) {
    wp_body(W1l, Wp1, (b - 5000) * 256 + tid, 128, 512, 0, 0, 256);
  } else if (b < 5512) {
    wp_body(W1r, Wp1, (b - 5256) * 256 + tid, 128, 512, 0, 128, 256);
  } else if (b < 6024) {
    wp_body(W2l, Wp2, (b - 5512) * 256 + tid, 512, 256, 0, 0, 512);
  } else if (b < 6536) {
    wp_body(W2r, Wp2, (b - 6024) * 256 + tid, 512, 256, 256, 0, 512);
  } else if (b < 6538) {
    int i = (b - 6536) * 256 + tid;
    if (i < 512) bc[i] = (i < 256) ? 0.f : b2[i - 256];
  } else {
    int e = (b - 6538) * 256 + tid;
    if (e < N_EDGES) atomicAdd(&deg[ei[N_EDGES + e]], 1);
  }
}

// ---------------- aggregation ----------------
// agg1: 4 nodes per 256-thread block, wave = node. colidx read coalesced
// into a lane register, neighbor ids broadcast via readlane. No LDS/barriers.
__global__ __launch_bounds__(256) void agg1_kernel(
    const ushort_t* __restrict__ Xb, ushort_t* __restrict__ Yb,
    const int* __restrict__ rowptr, const int* __restrict__ colidx) {
  const int wave = threadIdx.x >> 6, lane = threadIdx.x & 63;
  const int n = blockIdx.x * 4 + wave;
  const int s = rowptr[n], e = rowptr[n + 1];
  float s0 = 0.f, s1 = 0.f;
  for (int base = s; base < e; base += 64) {
    int cnt = min(64, e - base);
    int c = (base + lane < e) ? colidx[base + lane] : 0;  // coalesced
    int j = 0;
    for (; j + 8 <= cnt; j += 8) {
      unsigned int v[8];
      #pragma unroll
      for (int u = 0; u < 8; ++u) {
        int col = __builtin_amdgcn_readlane(c, j + u);
        v[u] = *(const unsigned int*)(Xb + (size_t)col * F_IN + 2 * lane);
      }
      #pragma unroll
      for (int u = 0; u < 8; ++u) {
        s0 += bf2f((ushort_t)(v[u] & 0xffffu));
        s1 += bf2f((ushort_t)(v[u] >> 16));
      }
    }
    for (; j < cnt; ++j) {
      int col = __builtin_amdgcn_readlane(c, j);
      unsigned int v = *(const unsigned int*)(Xb + (size_t)col * F_IN + 2 * lane);
      s0 += bf2f((ushort_t)(v & 0xffffu));
      s1 += bf2f((ushort_t)(v >> 16));
    }
  }
  float inv = 1.f / fmaxf((float)(e - s), 1.f);
  unsigned int o = (unsigned int)f2bf(s0 * inv) | ((unsigned int)f2bf(s1 * inv) << 16);
  *(unsigned int*)(Yb + (size_t)n * F_IN + 2 * lane) = o;
}

__global__ void agg2_kernel(const ushort_t* __restrict__ hl, const float* __restrict__ hr,
                            float* __restrict__ out,
                            const int* __restrict__ rowptr, const int* __restrict__ colidx) {
  __shared__ int cols[128];
  int n = blockIdx.x, f = threadIdx.x;
  int s = rowptr[n], e = rowptr[n + 1];
  float2 hrv = *(const float2*)(hr + (size_t)n * F_OUT + 2 * f);  // hoisted stream
  float s0 = 0.f, s1 = 0.f;
  for (int base = s; base < e; base += 128) {
    int cnt = min(128, e - base);
    __syncthreads();
    if (f < cnt) cols[f] = colidx[base + f];
    __syncthreads();
    int j = 0;
    for (; j + 8 <= cnt; j += 8) {  // 8 gathers in flight
      unsigned int v[8];
      #pragma unroll
      for (int u = 0; u < 8; ++u)
        v[u] = *(const unsigned int*)(hl + (size_t)cols[j + u] * F_OUT + 2 * f);
      #pragma unroll
      for (int u = 0; u < 8; ++u) {
        s0 += bf2f((ushort_t)(v[u] & 0xffffu));
        s1 += bf2f((ushort_t)(v[u] >> 16));
      }
    }
    for (; j < cnt; ++j) {
      unsigned int v = *(const unsigned int*)(hl + (size_t)cols[j] * F_OUT + 2 * f);
      s0 += bf2f((ushort_t)(v & 0xffffu));
      s1 += bf2f((ushort_t)(v >> 16));
    }
  }
  float inv = 1.f / fmaxf((float)(e - s), 1.f);
  float2 o;
  o.x = s0 * inv + hrv.x;
  o.y = s1 * inv + hrv.y;
  *(float2*)(out + (size_t)n * F_OUT + 2 * f) = o;
}

// ---------------- fused two-layer bf16 MFMA GEMM (aliased LDS) ----------------
// Per 32-row M-tile (grid 1250, 512 threads / 8 waves, wave w owns cols
// w*64..w*64+63 of the 512-wide output of each layer):
//   stage [aggx|x] panel into Pan[0:16K] (kc-major + XOR swizzle)
//   barrier; K-loop 1 (KT=256, Wp1) -> acc1
//   barrier (all waves done reading A); epilogue 1: relu(acc1+b1) -> bf16
//     -> Pan[0:32K] (same swizzled layout the A-reader expects)
//   barrier; K-loop 2 (KT=512, A = Pan, Wp2) -> acc2
//   epilogue 2: cols<256 -> hl bf16, cols>=256 -> hr fp32 (+biascat)
// LDS = ONE 32 KB buffer (4 blocks/CU = 32 waves, slot cap). B: register
// double-buffer, coalesced 1 KB wave-loads; no barriers inside K-loops.
__device__ __forceinline__ void mm32(const ushort_t* Apan, int k, int qk, int lm,
                                     bf16x8 f0, bf16x8 f1, bf16x8 f2, bf16x8 f3,
                                     floatx4 (&acc)[2][4]) {
  const int kc = k / 8 + qk;
  size_t o0 = ((size_t)(kc * 32 + lm) * 16) ^ (size_t)((kc & 7) << 4);
  bf16x8 av0 = *(const bf16x8*)((const char*)Apan + o0);
  bf16x8 av1 = *(const bf16x8*)((const char*)Apan + (o0 ^ 256));  // rows 16..31
  acc[0][0] = __builtin_amdgcn_mfma_f32_16x16x32_bf16(f0, av0, acc[0][0], 0, 0, 0);
  acc[0][1] = __builtin_amdgcn_mfma_f32_16x16x32_bf16(f1, av0, acc[0][1], 0, 0, 0);
  acc[0][2] = __builtin_amdgcn_mfma_f32_16x16x32_bf16(f2, av0, acc[0][2], 0, 0, 0);
  acc[0][3] = __builtin_amdgcn_mfma_f32_16x16x32_bf16(f3, av0, acc[0][3], 0, 0, 0);
  acc[1][0] = __builtin_amdgcn_mfma_f32_16x16x32_bf16(f0, av1, acc[1][0], 0, 0, 0);
  acc[1][1] = __builtin_amdgcn_mfma_f32_16x16x32_bf16(f1, av1, acc[1][1], 0, 0, 0);
  acc[1][2] = __builtin_amdgcn_mfma_f32_16x16x32_bf16(f2, av1, acc[1][2], 0, 0, 0);
  acc[1][3] = __builtin_amdgcn_mfma_f32_16x16x32_bf16(f3, av1, acc[1][3], 0, 0, 0);
}

__global__ __launch_bounds__(512) void gemm_fused(
    const ushort_t* __restrict__ A0,   // aggx  [40000][128]
    const ushort_t* __restrict__ A1,   // x     [40000][128]
    const ushort_t* __restrict__ Wp1,  // packed layer-1 weights (KT=256)
    const float* __restrict__ b1,
    const ushort_t* __restrict__ Wp2,  // packed layer-2 weights (KT=512)
    const float* __restrict__ bc,      // [0 | b2]
    float* __restrict__ hr, ushort_t* __restrict__ hl) {
  __shared__ ushort_t Pan[32 * 512];   // 32 KB: A panel (first 16 KB), then H
  const int tid = threadIdx.x;
  const int wave = tid >> 6, lane = tid & 63;
  const int lm = lane & 15, qk = lane >> 4;
  const int bm = blockIdx.x * 32;      // 1250 * 32 = 40000, no tail

  const ushort_t* wpg1 = Wp1 + (size_t)wave * 8 * 2048;   // (256/32) t-blocks
  const ushort_t* wpg2 = Wp2 + (size_t)wave * 16 * 2048;  // (512/32) t-blocks
#define LDB1(t, ni) (*(const bf16x8*)(wpg1 + ((size_t)(t) * 4 + (ni)) * 512 + lane * 8))
#define LDB2(t, ni) (*(const bf16x8*)(wpg2 + ((size_t)(t) * 4 + (ni)) * 512 + lane * 8))

  // ---- stage [aggx|x] panel: 32 rows x 32 chunks, 2 chunks per thread ----
  #pragma unroll
  for (int q = 0; q < 2; ++q) {
    int c = tid + q * 512;
    int lc = c & 31;              // chunk (k / 8)
    int row = c >> 5;
    const ushort_t* src = (lc >= 16)
        ? A1 + (size_t)(bm + row) * 128 + (lc - 16) * 8
        : A0 + (size_t)(bm + row) * 128 + lc * 8;
    bf16x8 v = *(const bf16x8*)src;
    size_t off = ((size_t)(lc * 32 + row) * 16) ^ (size_t)((lc & 7) << 4);
    *(bf16x8*)((char*)Pan + off) = v;
  }

  bf16x8 bvA[4], bvB[4];
  #pragma unroll
  for (int ni = 0; ni < 4; ++ni) bvA[ni] = LDB1(0, ni);
  __syncthreads();  // barrier 1: A panel visible

  // ---- K-loop 1 (KT = 256) ----
  floatx4 acc1[2][4] = {};
  #pragma unroll 1
  for (int kb = 0; kb < 256; kb += 64) {
    const int t0 = kb / 32;
    #pragma unroll
    for (int ni = 0; ni < 4; ++ni) bvB[ni] = LDB1(t0 + 1, ni);
    mm32(Pan, kb, qk, lm, bvA[0], bvA[1], bvA[2], bvA[3], acc1);
    if (kb + 64 < 256) {
      #pragma unroll
      for (int ni = 0; ni < 4; ++ni) bvA[ni] = LDB1(t0 + 2, ni);
    }
    mm32(Pan, kb + 32, qk, lm, bvB[0], bvB[1], bvB[2], bvB[3], acc1);
  }

  #pragma unroll
  for (int ni = 0; ni < 4; ++ni) bvA[ni] = LDB2(0, ni);  // issue before barriers
  __syncthreads();  // barrier 2: all waves done READING A before H overwrites

  // ---- epilogue 1: relu(acc1 + b1) -> bf16 -> Pan (swizzled, full 32 KB) ----
  #pragma unroll
  for (int ni = 0; ni < 4; ++ni) {
    int colg = wave * 64 + ni * 16 + qk * 4;
    float4 b4 = *(const float4*)&b1[colg];
    int lc2 = colg >> 3;
    int sub = (qk & 1) * 8;  // byte offset within the 16-B chunk
    #pragma unroll
    for (int mi = 0; mi < 2; ++mi) {
      int row = mi * 16 + lm;
      ushort4 o;
      o.x = f2bf(fmaxf(acc1[mi][ni][0] + b4.x, 0.f));
      o.y = f2bf(fmaxf(acc1[mi][ni][1] + b4.y, 0.f));
      o.z = f2bf(fmaxf(acc1[mi][ni][2] + b4.z, 0.f));
      o.w = f2bf(fmaxf(acc1[mi][ni][3] + b4.w, 0.f));
      size_t off = (((size_t)(lc2 * 32 + row) * 16) ^ (size_t)((lc2 & 7) << 4)) + sub;
      *(ushort4*)((char*)Pan + off) = o;
    }
  }
  __syncthreads();  // barrier 3: H panel visible

  // ---- K-loop 2 (KT = 512, A = Pan) ----
  floatx4 acc2[2][4] = {};
  #pragma unroll 1
  for (int kb = 0; kb < 512; kb += 64) {
    const int t0 = kb / 32;
    #pragma unroll
    for (int ni = 0; ni < 4; ++ni) bvB[ni] = LDB2(t0 + 1, ni);
    mm32(Pan, kb, qk, lm, bvA[0], bvA[1], bvA[2], bvA[3], acc2);
    if (kb + 64 < 512) {
      #pragma unroll
      for (int ni = 0; ni < 4; ++ni) bvA[ni] = LDB2(t0 + 2, ni);
    }
    mm32(Pan, kb + 32, qk, lm, bvB[0], bvB[1], bvB[2], bvB[3], acc2);
  }
#undef LDB1
#undef LDB2

  // ---- epilogue 2: cols<256 -> hl bf16, cols>=256 -> hr fp32 ----
  #pragma unroll
  for (int ni = 0; ni < 4; ++ni) {
    int colg = wave * 64 + ni * 16 + qk * 4;
    float4 b4 = *(const float4*)&bc[colg];
    #pragma unroll
    for (int mi = 0; mi < 2; ++mi) {
      int rowg = bm + mi * 16 + lm;
      float v0 = acc2[mi][ni][0] + b4.x;
      float v1 = acc2[mi][ni][1] + b4.y;
      float v2 = acc2[mi][ni][2] + b4.z;
      float v3 = acc2[mi][ni][3] + b4.w;
      if (colg < 256) {
        ushort4 o = {f2bf(v0), f2bf(v1), f2bf(v2), f2bf(v3)};
        *(ushort4*)&hl[(size_t)rowg * 256 + colg] = o;
      } else {
        float4 o = {v0, v1, v2, v3};
        *(float4*)&hr[(size_t)rowg * 256 + (colg - 256)] = o;
      }
    }
  }
}

extern "C" void kernel_launch(void* const* d_in, const int* in_sizes, int n_in,
                              void* d_out, int out_size, void* d_ws, size_t ws_size,
                              hipStream_t stream) {
  const float* x = (const float*)d_in[0];
  const int* ei = (const int*)d_in[1];  // int32 per harness, [2][E]
  const float* W1l = (const float*)d_in[2];
  const float* b1 = (const float*)d_in[3];
  const float* W1r = (const float*)d_in[4];
  const float* W2l = (const float*)d_in[5];
  const float* b2 = (const float*)d_in[6];
  const float* W2r = (const float*)d_in[7];
  float* out = (float*)d_out;

  char* ws = (char*)d_ws;
  size_t off = 0;
  auto alloc = [&](size_t bytes) {
    void* p = ws + off;
    off = (off + bytes + 255) & ~(size_t)255;
    return p;
  };
  int* deg = (int*)alloc((size_t)N_NODES * 4);
  int* rowptr = (int*)alloc((size_t)(N_NODES + 1) * 4);
  int* cursor = (int*)alloc((size_t)N_NODES * 4);
  int* col = (int*)alloc((size_t)N_EDGES * 4);
  int* bsum = (int*)alloc((size_t)NB_SCAN * 4);
  int* boff = (int*)alloc((size_t)NB_SCAN * 4);
  ushort_t* x_bf = (ushort_t*)alloc((size_t)N_NODES * F_IN * 2);
  ushort_t* aggx_bf = (ushort_t*)alloc((size_t)N_NODES * F_IN * 2);
  ushort_t* hl_bf = (ushort_t*)alloc((size_t)N_NODES * F_OUT * 2);  // h@W2l, bf16
  float* hr = (float*)alloc((size_t)N_NODES * F_OUT * 4);           // h@W2r + b2
  ushort_t* Wp1 = (ushort_t*)alloc((size_t)512 * 256 * 2);   // packed [W1l^T|W1r^T]
  ushort_t* Wp2 = (ushort_t*)alloc((size_t)512 * 512 * 2);   // packed [W2l|W2r]
  float* biascat = (float*)alloc(512 * 4);

  // Fused preprocessing: cvt_x + 4x wp + biascat + deg (independent work)
  hipMemsetAsync(deg, 0, (size_t)N_NODES * 4, stream);
  prep_kernel<<<PREP_BLOCKS, 256, 0, stream>>>(
      x, x_bf, W1l, W1r, W2l, W2r, Wp1, Wp2, b2, biascat, ei, deg);

  // CSR build
  scanA_kernel<<<NB_SCAN, 256, 0, stream>>>(deg, bsum);
  scanB_kernel<<<1, 256, 0, stream>>>(bsum, boff);
  scanC_kernel<<<NB_SCAN, 256, 0, stream>>>(deg, boff, rowptr, cursor);
  fill_kernel<<<(N_EDGES + 255) / 256, 256, 0, stream>>>(ei, cursor, col);

  // Layer 1 aggregation, then fused [layer1 GEMM -> LDS -> layer2 GEMM]
  agg1_kernel<<<N_NODES / 4, 256, 0, stream>>>(x_bf, aggx_bf, rowptr, col);
  gemm_fused<<<1250, 512, 0, stream>>>(
      aggx_bf, x_bf, Wp1, b1, Wp2, biascat, hr, hl_bf);
  // out = mean-agg(hl_bf) + hr
  agg2_kernel<<<N_NODES, 128, 0, stream>>>(hl_bf, hr, out, rowptr, col);
}

// Round 10
// 274.463 us; speedup vs baseline: 1.0322x; 1.0322x over previous
//
#include <hip/hip_runtime.h>

// GraphSAGE 2-layer. N=40000, E=640000, 128 -> 512 (relu) -> 256.
// Round 17: fused GEMM at BM=64 -- halve the B stream. Round-16 alias
// disproved LDS-residency as the limiter (LDS 48->32 KB, occupancy flat
// 34%, time flat). The invariant across all 5 flat GEMM variants is the
// weight stream: every block reads ALL of Wp1+Wp2 = 768 KB from L2;
// grid 1250 -> 960 MB total = 3.75 MB/CU at ~60 B/cyc/CU L2 share ->
// >=26 us floor, which is where every variant landed (x2 inefficiency).
// Occupancy can't help: resident blocks share the CU's L2 port. The lever
// is arithmetic intensity on B = BM. BM=64 (grid 625): 480 MB, 13 us
// floor. LDS = one aliased 64 KB panel (A 32 KB -> H 64 KB), 2 blocks/CU;
// acc[4][4]; compiler reuses acc1/acc2 (round-15: 44 VGPR) -> ~80 VGPR.
// prep/CSR/agg1/agg2 unchanged; agg2 fetch-bound ~52 us.

#define N_NODES 40000
#define N_EDGES 640000
#define F_IN 128
#define F_HID 512
#define F_OUT 256
#define NB_SCAN 157  // ceil(40000/256)

typedef unsigned short ushort_t;
typedef __attribute__((ext_vector_type(8))) short bf16x8;
typedef __attribute__((ext_vector_type(4))) float floatx4;

__device__ __forceinline__ ushort_t f2bf(float f) {
  union { float f; unsigned int u; } x; x.f = f;
  unsigned int r = (x.u + 0x7FFFu + ((x.u >> 16) & 1u)) >> 16;  // RNE
  return (ushort_t)r;
}
__device__ __forceinline__ float bf2f(ushort_t u) {
  union { unsigned int u; float f; } x; x.u = ((unsigned int)u) << 16;
  return x.f;
}

// ---------------- CSR build (scans + fill) ----------------
__global__ void scanA_kernel(const int* __restrict__ deg, int* __restrict__ bsum) {
  __shared__ int sdata[256];
  int i = blockIdx.x * 256 + threadIdx.x;
  sdata[threadIdx.x] = (i < N_NODES) ? deg[i] : 0;
  __syncthreads();
  #pragma unroll
  for (int off = 128; off > 0; off >>= 1) {
    if (threadIdx.x < off) sdata[threadIdx.x] += sdata[threadIdx.x + off];
    __syncthreads();
  }
  if (threadIdx.x == 0) bsum[blockIdx.x] = sdata[0];
}

__global__ void scanB_kernel(const int* __restrict__ bsum, int* __restrict__ boff) {
  __shared__ int buf[2][256];
  int tid = threadIdx.x;
  int v = (tid < NB_SCAN) ? bsum[tid] : 0;
  buf[0][tid] = v;
  __syncthreads();
  int cur = 0;
  #pragma unroll
  for (int off = 1; off < 256; off <<= 1) {
    int val = buf[cur][tid];
    if (tid >= off) val += buf[cur][tid - off];
    buf[cur ^ 1][tid] = val;
    __syncthreads();
    cur ^= 1;
  }
  if (tid < NB_SCAN) boff[tid] = buf[cur][tid] - v;  // exclusive
}

__global__ void scanC_kernel(const int* __restrict__ deg, const int* __restrict__ boff,
                             int* __restrict__ rowptr, int* __restrict__ cursor) {
  __shared__ int buf[2][256];
  int tid = threadIdx.x;
  int i = blockIdx.x * 256 + tid;
  int v = (i < N_NODES) ? deg[i] : 0;
  buf[0][tid] = v;
  __syncthreads();
  int cur = 0;
  #pragma unroll
  for (int off = 1; off < 256; off <<= 1) {
    int val = buf[cur][tid];
    if (tid >= off) val += buf[cur][tid - off];
    buf[cur ^ 1][tid] = val;
    __syncthreads();
    cur ^= 1;
  }
  if (i < N_NODES) {
    int ex = boff[blockIdx.x] + buf[cur][tid] - v;
    rowptr[i] = ex;
    cursor[i] = ex;
    if (i == N_NODES - 1) rowptr[N_NODES] = ex + v;  // == E
  }
}

__global__ void fill_kernel(const int* __restrict__ ei, int* __restrict__ cursor,
                            int* __restrict__ col) {
  int e = blockIdx.x * blockDim.x + threadIdx.x;
  if (e < N_EDGES) {
    int d = ei[N_EDGES + e];
    int s = ei[e];
    int pos = atomicAdd(&cursor[d], 1);
    col[pos] = s;
  }
}

// ---------------- fused preprocessing ----------------
// Wp pack: element (n_global = rowoff+n, k_global = koff+k) at
//   Wp[((gg*(KT/32) + t)*4 + ni)*512 + (qk*16 + lm)*8 + j]
// gg=n>>6, ni=(n>>4)&3, lm=n&15, c=kg>>3, j=kg&7, t=c>>2, qk=c&3.
__device__ __forceinline__ void wp_body(const float* __restrict__ W,
                                        ushort_t* __restrict__ Wp,
                                        int i, int K, int N, int rowoff, int koff,
                                        int KT) {
  if (i < K * N) {
    int n = i / K, k = i - n * K;
    int ng = rowoff + n, kg = koff + k;
    int gg = ng >> 6, ni = (ng >> 4) & 3, lm = ng & 15;
    int c = kg >> 3, j = kg & 7, t = c >> 2, qk = c & 3;
    size_t dst = (((size_t)(gg * (KT / 32) + t) * 4 + ni) * 64 + qk * 16 + lm) * 8 + j;
    Wp[dst] = f2bf(W[(size_t)k * N + n]);
  }
}

// block ranges: [0,5000) cvt_x | [5000,5256) W1l | [5256,5512) W1r
// [5512,6024) W2l | [6024,6536) W2r | [6536,6538) biascat | [6538,9038) deg
#define PREP_BLOCKS 9038
__global__ void prep_kernel(const float* __restrict__ x, ushort_t* __restrict__ xb,
                            const float* __restrict__ W1l, const float* __restrict__ W1r,
                            const float* __restrict__ W2l, const float* __restrict__ W2r,
                            ushort_t* __restrict__ Wp1, ushort_t* __restrict__ Wp2,
                            const float* __restrict__ b2, float* __restrict__ bc,
                            const int* __restrict__ ei, int* __restrict__ deg) {
  int b = blockIdx.x, tid = threadIdx.x;
  if (b < 5000) {
    int i = b * 256 + tid;  // per float4
    const int n4 = (N_NODES * F_IN) / 4;
    if (i < n4) {
      float4 v = ((const float4*)x)[i];
      ushort4 o;
      o.x = f2bf(v.x); o.y = f2bf(v.y); o.z = f2bf(v.z); o.w = f2bf(v.w);
      ((ushort4*)xb)[i] = o;
    }
  } else if (b < 5256) {
    wp_body(W1l, Wp1, (b - 5000) * 256 + tid, 128, 512, 0, 0, 256);
  } else if (b < 5512) {
    wp_body(W1r, Wp1, (b - 5256) * 256 + tid, 128, 512, 0, 128, 256);
  } else if (b < 6024) {
    wp_body(W2l, Wp2, (b - 5512) * 256 + tid, 512, 256, 0, 0, 512);
  } else if (b < 6536) {
    wp_body(W2r, Wp2, (b - 6024) * 256 + tid, 512, 256, 256, 0, 512);
  } else if (b < 6538) {
    int i = (b - 6536) * 256 + tid;
    if (i < 512) bc[i] = (i < 256) ? 0.f : b2[i - 256];
  } else {
    int e = (b - 6538) * 256 + tid;
    if (e < N_EDGES) atomicAdd(&deg[ei[N_EDGES + e]], 1);
  }
}

// ---------------- aggregation ----------------
// agg1: 4 nodes per 256-thread block, wave = node. colidx read coalesced
// into a lane register, neighbor ids broadcast via readlane. No LDS/barriers.
__global__ __launch_bounds__(256) void agg1_kernel(
    const ushort_t* __restrict__ Xb, ushort_t* __restrict__ Yb,
    const int* __restrict__ rowptr, const int* __restrict__ colidx) {
  const int wave = threadIdx.x >> 6, lane = threadIdx.x & 63;
  const int n = blockIdx.x * 4 + wave;
  const int s = rowptr[n], e = rowptr[n + 1];
  float s0 = 0.f, s1 = 0.f;
  for (int base = s; base < e; base += 64) {
    int cnt = min(64, e - base);
    int c = (base + lane < e) ? colidx[base + lane] : 0;  // coalesced
    int j = 0;
    for (; j + 8 <= cnt; j += 8) {
      unsigned int v[8];
      #pragma unroll
      for (int u = 0; u < 8; ++u) {
        int col = __builtin_amdgcn_readlane(c, j + u);
        v[u] = *(const unsigned int*)(Xb + (size_t)col * F_IN + 2 * lane);
      }
      #pragma unroll
      for (int u = 0; u < 8; ++u) {
        s0 += bf2f((ushort_t)(v[u] & 0xffffu));
        s1 += bf2f((ushort_t)(v[u] >> 16));
      }
    }
    for (; j < cnt; ++j) {
      int col = __builtin_amdgcn_readlane(c, j);
      unsigned int v = *(const unsigned int*)(Xb + (size_t)col * F_IN + 2 * lane);
      s0 += bf2f((ushort_t)(v & 0xffffu));
      s1 += bf2f((ushort_t)(v >> 16));
    }
  }
  float inv = 1.f / fmaxf((float)(e - s), 1.f);
  unsigned int o = (unsigned int)f2bf(s0 * inv) | ((unsigned int)f2bf(s1 * inv) << 16);
  *(unsigned int*)(Yb + (size_t)n * F_IN + 2 * lane) = o;
}

__global__ void agg2_kernel(const ushort_t* __restrict__ hl, const float* __restrict__ hr,
                            float* __restrict__ out,
                            const int* __restrict__ rowptr, const int* __restrict__ colidx) {
  __shared__ int cols[128];
  int n = blockIdx.x, f = threadIdx.x;
  int s = rowptr[n], e = rowptr[n + 1];
  float2 hrv = *(const float2*)(hr + (size_t)n * F_OUT + 2 * f);  // hoisted stream
  float s0 = 0.f, s1 = 0.f;
  for (int base = s; base < e; base += 128) {
    int cnt = min(128, e - base);
    __syncthreads();
    if (f < cnt) cols[f] = colidx[base + f];
    __syncthreads();
    int j = 0;
    for (; j + 8 <= cnt; j += 8) {  // 8 gathers in flight
      unsigned int v[8];
      #pragma unroll
      for (int u = 0; u < 8; ++u)
        v[u] = *(const unsigned int*)(hl + (size_t)cols[j + u] * F_OUT + 2 * f);
      #pragma unroll
      for (int u = 0; u < 8; ++u) {
        s0 += bf2f((ushort_t)(v[u] & 0xffffu));
        s1 += bf2f((ushort_t)(v[u] >> 16));
      }
    }
    for (; j < cnt; ++j) {
      unsigned int v = *(const unsigned int*)(hl + (size_t)cols[j] * F_OUT + 2 * f);
      s0 += bf2f((ushort_t)(v & 0xffffu));
      s1 += bf2f((ushort_t)(v >> 16));
    }
  }
  float inv = 1.f / fmaxf((float)(e - s), 1.f);
  float2 o;
  o.x = s0 * inv + hrv.x;
  o.y = s1 * inv + hrv.y;
  *(float2*)(out + (size_t)n * F_OUT + 2 * f) = o;
}

// ---------------- fused two-layer bf16 MFMA GEMM, BM=64, aliased LDS ----
// Per 64-row M-tile (grid 625, 512 threads / 8 waves, wave w owns cols
// w*64..w*64+63 of the 512-wide output of each layer):
//   stage [aggx|x] panel into Pan[0:32K] (kc-major, 64 rows/kc, XOR swz)
//   barrier; K-loop 1 (KT=256, Wp1) -> acc1[4][4]
//   barrier; epilogue 1: relu(acc1+b1) -> bf16 -> Pan[0:64K] (same layout)
//   barrier; K-loop 2 (KT=512, A = Pan, Wp2) -> acc2[4][4]
//   epilogue 2: cols<256 -> hl bf16, cols>=256 -> hr fp32 (+biascat)
// LDS = ONE 64 KB buffer -> 2 blocks/CU. B: register double-buffer,
// coalesced 1 KB wave-loads; each B t-block now feeds 16 MFMAs (256 B
// per MFMA vs 512 at BM=32) -> per-block B bytes amortized over 2x rows.
__device__ __forceinline__ void mm64(const ushort_t* Pan, int k, int qk, int lm,
                                     bf16x8 f0, bf16x8 f1, bf16x8 f2, bf16x8 f3,
                                     floatx4 (&acc)[4][4]) {
  const int kc = k / 8 + qk;
  #pragma unroll
  for (int mi = 0; mi < 4; ++mi) {
    size_t o = ((size_t)(kc * 64 + mi * 16 + lm) * 16) ^ (size_t)((kc & 7) << 4);
    bf16x8 av = *(const bf16x8*)((const char*)Pan + o);
    acc[mi][0] = __builtin_amdgcn_mfma_f32_16x16x32_bf16(f0, av, acc[mi][0], 0, 0, 0);
    acc[mi][1] = __builtin_amdgcn_mfma_f32_16x16x32_bf16(f1, av, acc[mi][1], 0, 0, 0);
    acc[mi][2] = __builtin_amdgcn_mfma_f32_16x16x32_bf16(f2, av, acc[mi][2], 0, 0, 0);
    acc[mi][3] = __builtin_amdgcn_mfma_f32_16x16x32_bf16(f3, av, acc[mi][3], 0, 0, 0);
  }
}

__global__ __launch_bounds__(512) void gemm_fused(
    const ushort_t* __restrict__ A0,   // aggx  [40000][128]
    const ushort_t* __restrict__ A1,   // x     [40000][128]
    const ushort_t* __restrict__ Wp1,  // packed layer-1 weights (KT=256)
    const float* __restrict__ b1,
    const ushort_t* __restrict__ Wp2,  // packed layer-2 weights (KT=512)
    const float* __restrict__ bc,      // [0 | b2]
    float* __restrict__ hr, ushort_t* __restrict__ hl) {
  __shared__ ushort_t Pan[64 * 512];   // 64 KB: A panel (first 32 KB), then H
  const int tid = threadIdx.x;
  const int wave = tid >> 6, lane = tid & 63;
  const int lm = lane & 15, qk = lane >> 4;
  const int bm = blockIdx.x * 64;      // 625 * 64 = 40000, no tail

  const ushort_t* wpg1 = Wp1 + (size_t)wave * 8 * 2048;   // (256/32) t-blocks
  const ushort_t* wpg2 = Wp2 + (size_t)wave * 16 * 2048;  // (512/32) t-blocks
#define LDB1(t, ni) (*(const bf16x8*)(wpg1 + ((size_t)(t) * 4 + (ni)) * 512 + lane * 8))
#define LDB2(t, ni) (*(const bf16x8*)(wpg2 + ((size_t)(t) * 4 + (ni)) * 512 + lane * 8))

  // ---- stage [aggx|x] panel: 64 rows x 32 chunks, 4 chunks per thread ----
  #pragma unroll
  for (int q = 0; q < 4; ++q) {
    int c = tid + q * 512;
    int lc = c & 31;              // chunk (k / 8)
    int row = c >> 5;             // 0..63
    const ushort_t* src = (lc >= 16)
        ? A1 + (size_t)(bm + row) * 128 + (lc - 16) * 8
        : A0 + (size_t)(bm + row) * 128 + lc * 8;
    bf16x8 v = *(const bf16x8*)src;
    size_t off = ((size_t)(lc * 64 + row) * 16) ^ (size_t)((lc & 7) << 4);
    *(bf16x8*)((char*)Pan + off) = v;
  }

  bf16x8 bvA[4], bvB[4];
  #pragma unroll
  for (int ni = 0; ni < 4; ++ni) bvA[ni] = LDB1(0, ni);
  __syncthreads();  // barrier 1: A panel visible

  // ---- K-loop 1 (KT = 256) ----
  floatx4 acc1[4][4] = {};
  #pragma unroll 1
  for (int kb = 0; kb < 256; kb += 64) {
    const int t0 = kb / 32;
    #pragma unroll
    for (int ni = 0; ni < 4; ++ni) bvB[ni] = LDB1(t0 + 1, ni);
    mm64(Pan, kb, qk, lm, bvA[0], bvA[1], bvA[2], bvA[3], acc1);
    if (kb + 64 < 256) {
      #pragma unroll
      for (int ni = 0; ni < 4; ++ni) bvA[ni] = LDB1(t0 + 2, ni);
    }
    mm64(Pan, kb + 32, qk, lm, bvB[0], bvB[1], bvB[2], bvB[3], acc1);
  }

  #pragma unroll
  for (int ni = 0; ni < 4; ++ni) bvA[ni] = LDB2(0, ni);  // issue before barriers
  __syncthreads();  // barrier 2: all waves done READING A before H overwrites

  // ---- epilogue 1: relu(acc1 + b1) -> bf16 -> Pan (swizzled, full 64 KB) ----
  #pragma unroll
  for (int ni = 0; ni < 4; ++ni) {
    int colg = wave * 64 + ni * 16 + qk * 4;
    float4 b4 = *(const float4*)&b1[colg];
    int lc2 = colg >> 3;
    int sub = (qk & 1) * 8;  // byte offset within the 16-B chunk
    #pragma unroll
    for (int mi = 0; mi < 4; ++mi) {
      int row = mi * 16 + lm;
      ushort4 o;
      o.x = f2bf(fmaxf(acc1[mi][ni][0] + b4.x, 0.f));
      o.y = f2bf(fmaxf(acc1[mi][ni][1] + b4.y, 0.f));
      o.z = f2bf(fmaxf(acc1[mi][ni][2] + b4.z, 0.f));
      o.w = f2bf(fmaxf(acc1[mi][ni][3] + b4.w, 0.f));
      size_t off = (((size_t)(lc2 * 64 + row) * 16) ^ (size_t)((lc2 & 7) << 4)) + sub;
      *(ushort4*)((char*)Pan + off) = o;
    }
  }
  __syncthreads();  // barrier 3: H panel visible

  // ---- K-loop 2 (KT = 512, A = Pan) ----
  floatx4 acc2[4][4] = {};
  #pragma unroll 1
  for (int kb = 0; kb < 512; kb += 64) {
    const int t0 = kb / 32;
    #pragma unroll
    for (int ni = 0; ni < 4; ++ni) bvB[ni] = LDB2(t0 + 1, ni);
    mm64(Pan, kb, qk, lm, bvA[0], bvA[1], bvA[2], bvA[3], acc2);
    if (kb + 64 < 512) {
      #pragma unroll
      for (int ni = 0; ni < 4; ++ni) bvA[ni] = LDB2(t0 + 2, ni);
    }
    mm64(Pan, kb + 32, qk, lm, bvB[0], bvB[1], bvB[2], bvB[3], acc2);
  }
#undef LDB1
#undef LDB2

  // ---- epilogue 2: cols<256 -> hl bf16, cols>=256 -> hr fp32 ----
  #pragma unroll
  for (int ni = 0; ni < 4; ++ni) {
    int colg = wave * 64 + ni * 16 + qk * 4;
    float4 b4 = *(const float4*)&bc[colg];
    #pragma unroll
    for (int mi = 0; mi < 4; ++mi) {
      int rowg = bm + mi * 16 + lm;
      float v0 = acc2[mi][ni][0] + b4.x;
      float v1 = acc2[mi][ni][1] + b4.y;
      float v2 = acc2[mi][ni][2] + b4.z;
      float v3 = acc2[mi][ni][3] + b4.w;
      if (colg < 256) {
        ushort4 o = {f2bf(v0), f2bf(v1), f2bf(v2), f2bf(v3)};
        *(ushort4*)&hl[(size_t)rowg * 256 + colg] = o;
      } else {
        float4 o = {v0, v1, v2, v3};
        *(float4*)&hr[(size_t)rowg * 256 + (colg - 256)] = o;
      }
    }
  }
}

extern "C" void kernel_launch(void* const* d_in, const int* in_sizes, int n_in,
                              void* d_out, int out_size, void* d_ws, size_t ws_size,
                              hipStream_t stream) {
  const float* x = (const float*)d_in[0];
  const int* ei = (const int*)d_in[1];  // int32 per harness, [2][E]
  const float* W1l = (const float*)d_in[2];
  const float* b1 = (const float*)d_in[3];
  const float* W1r = (const float*)d_in[4];
  const float* W2l = (const float*)d_in[5];
  const float* b2 = (const float*)d_in[6];
  const float* W2r = (const float*)d_in[7];
  float* out = (float*)d_out;

  char* ws = (char*)d_ws;
  size_t off = 0;
  auto alloc = [&](size_t bytes) {
    void* p = ws + off;
    off = (off + bytes + 255) & ~(size_t)255;
    return p;
  };
  int* deg = (int*)alloc((size_t)N_NODES * 4);
  int* rowptr = (int*)alloc((size_t)(N_NODES + 1) * 4);
  int* cursor = (int*)alloc((size_t)N_NODES * 4);
  int* col = (int*)alloc((size_t)N_EDGES * 4);
  int* bsum = (int*)alloc((size_t)NB_SCAN * 4);
  int* boff = (int*)alloc((size_t)NB_SCAN * 4);
  ushort_t* x_bf = (ushort_t*)alloc((size_t)N_NODES * F_IN * 2);
  ushort_t* aggx_bf = (ushort_t*)alloc((size_t)N_NODES * F_IN * 2);
  ushort_t* hl_bf = (ushort_t*)alloc((size_t)N_NODES * F_OUT * 2);  // h@W2l, bf16
  float* hr = (float*)alloc((size_t)N_NODES * F_OUT * 4);           // h@W2r + b2
  ushort_t* Wp1 = (ushort_t*)alloc((size_t)512 * 256 * 2);   // packed [W1l^T|W1r^T]
  ushort_t* Wp2 = (ushort_t*)alloc((size_t)512 * 512 * 2);   // packed [W2l|W2r]
  float* biascat = (float*)alloc(512 * 4);

  // Fused preprocessing: cvt_x + 4x wp + biascat + deg (independent work)
  hipMemsetAsync(deg, 0, (size_t)N_NODES * 4, stream);
  prep_kernel<<<PREP_BLOCKS, 256, 0, stream>>>(
      x, x_bf, W1l, W1r, W2l, W2r, Wp1, Wp2, b2, biascat, ei, deg);

  // CSR build
  scanA_kernel<<<NB_SCAN, 256, 0, stream>>>(deg, bsum);
  scanB_kernel<<<1, 256, 0, stream>>>(bsum, boff);
  scanC_kernel<<<NB_SCAN, 256, 0, stream>>>(deg, boff, rowptr, cursor);
  fill_kernel<<<(N_EDGES + 255) / 256, 256, 0, stream>>>(ei, cursor, col);

  // Layer 1 aggregation, then fused [layer1 GEMM -> LDS -> layer2 GEMM]
  agg1_kernel<<<N_NODES / 4, 256, 0, stream>>>(x_bf, aggx_bf, rowptr, col);
  gemm_fused<<<625, 512, 0, stream>>>(
      aggx_bf, x_bf, Wp1, b1, Wp2, biascat, hr, hl_bf);
  // out = mean-agg(hl_bf) + hr
  agg2_kernel<<<N_NODES, 128, 0, stream>>>(hl_bf, hr, out, rowptr, col);
}